// Round 12
// baseline (269.715 us; speedup 1.0000x reference)
//
#include <hip/hip_runtime.h>
#include <stdint.h>

#define M_TOT 8192
#define K_TOT 4096
#define N_TOT 4096
#define GROUPQ 32

#define BM 256
#define BN 256
#define BK 64
#define NT (K_TOT / BK)   // 64 K-tiles

typedef __bf16 bf16x8 __attribute__((ext_vector_type(8)));
typedef float f32x4 __attribute__((ext_vector_type(4)));
typedef unsigned short u16;
typedef unsigned short u16x8 __attribute__((ext_vector_type(8)));

template <int V> struct IC { static constexpr int value = V; };

__device__ __forceinline__ u16 f2bf_rne(float f) {
  union { float f; uint32_t u; } v; v.f = f;
  uint32_t u = v.u;
  uint32_t r = (u + 0x7FFFu + ((u >> 16) & 1u)) >> 16;  // round-nearest-even
  return (u16)r;
}

// ---- merged prepass: (a) x fp32 -> bf16, (b) dequant nibbles -> bf16 W ----
__global__ void prep_kernel(const float* __restrict__ x, const int* __restrict__ wp,
                            const float* __restrict__ sc,
                            u16* __restrict__ xb, u16* __restrict__ wb) {
  const int NCVT = M_TOT * K_TOT / 8;   // 8-elem chunks of x
  const int KH = K_TOT / 2;
  const int NDQ = N_TOT * KH / 8;       // 8-int chunks of w_packed
  int stride = gridDim.x * blockDim.x;
  int tid0 = blockIdx.x * blockDim.x + threadIdx.x;

  for (int i = tid0; i < NCVT; i += stride) {
    const float4* p = (const float4*)(x + (size_t)i * 8);
    float4 a = p[0];
    float4 b = p[1];
    u16x8 o;
    o[0] = f2bf_rne(a.x); o[1] = f2bf_rne(a.y); o[2] = f2bf_rne(a.z); o[3] = f2bf_rne(a.w);
    o[4] = f2bf_rne(b.x); o[5] = f2bf_rne(b.y); o[6] = f2bf_rne(b.z); o[7] = f2bf_rne(b.w);
    *(u16x8*)(xb + (size_t)i * 8) = o;
  }

  for (int t = tid0; t < NDQ; t += stride) {
    int base = t * 8;
    int o = base >> 11;                 // / (KH=2048)
    int ci = base & 2047;
    int e0 = ci * 2;
    float scale = sc[o * (K_TOT / GROUPQ) + (e0 >> 5)];
    int4 p0 = *(const int4*)(wp + base);
    int4 p1 = *(const int4*)(wp + base + 4);
    int v[8] = {p0.x, p0.y, p0.z, p0.w, p1.x, p1.y, p1.z, p1.w};
    u16x8 oA, oB;
#pragma unroll
    for (int j = 0; j < 8; ++j) {
      float lo = (float)((v[j] & 0xF) - 8) * scale;
      float hi = (float)(((v[j] >> 4) & 0xF) - 8) * scale;
      u16 lob = f2bf_rne(lo), hib = f2bf_rne(hi);
      if (j < 4) { oA[2 * j] = lob; oA[2 * j + 1] = hib; }
      else       { oB[2 * (j - 4)] = lob; oB[2 * (j - 4) + 1] = hib; }
    }
    u16* dst = wb + (size_t)o * K_TOT + e0;
    *(u16x8*)dst = oA;
    *(u16x8*)(dst + 8) = oB;
  }
}

// ---- main GEMM: faithful m201 8-phase port onto the proven plane layout.
// 256x256, BK=64, 8 waves (2Mx4N), 16x16x32 MFMA, 128 KiB dbuf LDS.
// Per K-tile: 4 quadrant-phases, each = { same-phase ds_reads (12/4/8/0),
// stage 1 half-tile, [lgkmcnt(8) if 12 reads], s_barrier, lgkmcnt(0),
// setprio(1), 16 MFMA, setprio(0), s_barrier }.
// Stage stream: ph1 Bh1(t+1)->nbuf, ph2 Ah0(t+2)->buf, ph3 Bh0(t+2)->buf,
// ph4 Ah1(t+2)->buf; vmcnt(6) at ph4 only (3 half-tiles in flight).
// Hazards: each phase's reads drained by its own lgkm0 before the next
// phase's stage into those planes is issued (stages follow the post-MFMA
// barrier). Tail: clamped unconditional stages (dead writes = same data,
// reads pre-drained) keep vmcnt counts uniform. ----
__global__ __launch_bounds__(512, 2) void gemm_bf16_kernel(
    const u16* __restrict__ A, const u16* __restrict__ Bt,
    const float* __restrict__ bias, float* __restrict__ C) {
  __shared__ alignas(16) u16 sL[65536];  // 128 KiB: A = [0,32768), B = [32768,65536)

  const int ntn = N_TOT / BN;            // 16
  int wg = blockIdx.x, nwg = gridDim.x;  // 512, %8==0
  int cpx = nwg >> 3;
  int swz = (wg & 7) * cpx + (wg >> 3);  // bijective XCD swizzle
  int bm = swz / ntn, bn = swz % ntn;

  int tid = threadIdx.x, wid = tid >> 6, lane = tid & 63;
  int wr = wid >> 2, wc = wid & 3;       // 2M x 4N waves
  const size_t K = K_TOT;

  // ---- staging addressing: half-tile = 128 rows x 64 cols, stored as two
  // k-planes of [128][32]; LDS chunk c holds global chunk c ^ ((row>>1)&3) ----
  int rowS = tid >> 2;                   // 0..127
  int cgS = (tid & 3) ^ ((rowS >> 1) & 3);
  const u16* pA = A + ((size_t)(bm * 256 + (rowS >> 6) * 128 + (rowS & 63))) * K + cgS * 8;
  const u16* pB = Bt + ((size_t)(bn * 256 + (rowS >> 5) * 64 + (rowS & 31))) * K + cgS * 8;
  u16* sE = &sL[0];

#define GLLDS(src, dst)                                                      \
  __builtin_amdgcn_global_load_lds(                                          \
      (const __attribute__((address_space(1))) uint32_t*)(src),              \
      (__attribute__((address_space(3))) uint32_t*)(dst), 16, 0, 0)

  auto stA = [&](int T, int mh, auto bufc) {  // A half mh of tile T (2 gl_lds)
    constexpr int buf = decltype(bufc)::value;
    const u16* s = pA + (size_t)mh * 64 * K + (size_t)T * 64;
    GLLDS(s,      sE + ((buf * 2 + 0) * 2 + mh) * 4096 + tid * 8);
    GLLDS(s + 32, sE + ((buf * 2 + 1) * 2 + mh) * 4096 + tid * 8);
  };
  auto stB = [&](int T, int nh, auto bufc) {
    constexpr int buf = decltype(bufc)::value;
    const u16* s = pB + (size_t)nh * 32 * K + (size_t)T * 64;
    GLLDS(s,      sE + 32768 + ((buf * 2 + 0) * 2 + nh) * 4096 + tid * 8);
    GLLDS(s + 32, sE + 32768 + ((buf * 2 + 1) * 2 + nh) * 4096 + tid * 8);
  };

  // ---- reader addressing (0-conflict per plane, same involution) ----
  int rA = wr * 64 + (lane & 15);
  int cA = ((lane >> 4) ^ ((rA >> 1) & 3)) * 8;
  int rB = wc * 32 + (lane & 15);
  int cB = ((lane >> 4) ^ ((rB >> 1) & 3)) * 8;
  const u16* rdA = sE + rA * 32 + cA;            // + const plane/frag offsets
  const u16* rdB = sE + 32768 + rB * 32 + cB;
  auto ldA = [&](auto bufc, int kk, int mh, int m3) {
    constexpr int buf = decltype(bufc)::value;
    return *(const bf16x8*)(rdA + ((buf * 2 + kk) * 2 + mh) * 4096 + m3 * 16 * 32);
  };
  auto ldB = [&](auto bufc, int kk, int nh, int n2) {
    constexpr int buf = decltype(bufc)::value;
    return *(const bf16x8*)(rdB + ((buf * 2 + kk) * 2 + nh) * 4096 + n2 * 16 * 32);
  };

  f32x4 acc[8][4] = {};
  bf16x8 a0[4][2], a1[4][2], b0[2][2], b1[2][2];

  // ---- prologue (m201 counts): tile0's 4 halves (8 ops) -> vmcnt(4)
  // (Ah0/Bh0 landed); tile1's Ah0,Bh0,Ah1 (6 ops) -> vmcnt(6) (tile0 fully
  // landed, 3 half-tiles in flight); barrier. Bh1(1) staged at t0-ph1. ----
  stA(0, 0, IC<0>{}); stB(0, 0, IC<0>{}); stA(0, 1, IC<0>{}); stB(0, 1, IC<0>{});
  asm volatile("s_waitcnt vmcnt(4)" ::: "memory");
  stA(1, 0, IC<1>{}); stB(1, 0, IC<1>{}); stA(1, 1, IC<1>{});
  asm volatile("s_waitcnt vmcnt(6)" ::: "memory");
  __builtin_amdgcn_s_barrier();

  auto tile_body = [&](int t, auto bufc, auto nbufc) {
    int Tc1 = (t + 1 < NT) ? t + 1 : NT - 1;   // clamped (tail-safe, uniform vmcnt)
    int Tc2 = (t + 2 < NT) ? t + 2 : NT - 1;

    // ---- ph1 (Q00): read a0(8)+b0(4); stage Bh1(t+1)->nbuf ----
#pragma unroll
    for (int m3 = 0; m3 < 4; ++m3)
#pragma unroll
      for (int kk = 0; kk < 2; ++kk) a0[m3][kk] = ldA(bufc, kk, 0, m3);
#pragma unroll
    for (int n2 = 0; n2 < 2; ++n2)
#pragma unroll
      for (int kk = 0; kk < 2; ++kk) b0[n2][kk] = ldB(bufc, kk, 0, n2);
    stB(Tc1, 1, nbufc);
    asm volatile("s_waitcnt lgkmcnt(8)" ::: "memory");
    __builtin_amdgcn_s_barrier();
    asm volatile("s_waitcnt lgkmcnt(0)" ::: "memory");
    __builtin_amdgcn_s_setprio(1);
#pragma unroll
    for (int kk = 0; kk < 2; ++kk)
#pragma unroll
      for (int m3 = 0; m3 < 4; ++m3)
#pragma unroll
        for (int n2 = 0; n2 < 2; ++n2)
          acc[m3][n2] = __builtin_amdgcn_mfma_f32_16x16x32_bf16(a0[m3][kk], b0[n2][kk], acc[m3][n2], 0, 0, 0);
    __builtin_amdgcn_s_setprio(0);
    __builtin_amdgcn_s_barrier();

    // ---- ph2 (Q01): read b1(4); stage Ah0(t+2)->buf ----
#pragma unroll
    for (int n2 = 0; n2 < 2; ++n2)
#pragma unroll
      for (int kk = 0; kk < 2; ++kk) b1[n2][kk] = ldB(bufc, kk, 1, n2);
    stA(Tc2, 0, bufc);
    __builtin_amdgcn_s_barrier();
    asm volatile("s_waitcnt lgkmcnt(0)" ::: "memory");
    __builtin_amdgcn_s_setprio(1);
#pragma unroll
    for (int kk = 0; kk < 2; ++kk)
#pragma unroll
      for (int m3 = 0; m3 < 4; ++m3)
#pragma unroll
        for (int n2 = 0; n2 < 2; ++n2)
          acc[m3][n2 + 2] = __builtin_amdgcn_mfma_f32_16x16x32_bf16(a0[m3][kk], b1[n2][kk], acc[m3][n2 + 2], 0, 0, 0);
    __builtin_amdgcn_s_setprio(0);
    __builtin_amdgcn_s_barrier();

    // ---- ph3 (Q10): read a1(8); stage Bh0(t+2)->buf ----
#pragma unroll
    for (int m3 = 0; m3 < 4; ++m3)
#pragma unroll
      for (int kk = 0; kk < 2; ++kk) a1[m3][kk] = ldA(bufc, kk, 1, m3);
    stB(Tc2, 0, bufc);
    __builtin_amdgcn_s_barrier();
    asm volatile("s_waitcnt lgkmcnt(0)" ::: "memory");
    __builtin_amdgcn_s_setprio(1);
#pragma unroll
    for (int kk = 0; kk < 2; ++kk)
#pragma unroll
      for (int m3 = 0; m3 < 4; ++m3)
#pragma unroll
        for (int n2 = 0; n2 < 2; ++n2)
          acc[m3 + 4][n2] = __builtin_amdgcn_mfma_f32_16x16x32_bf16(a1[m3][kk], b0[n2][kk], acc[m3 + 4][n2], 0, 0, 0);
    __builtin_amdgcn_s_setprio(0);
    __builtin_amdgcn_s_barrier();

    // ---- ph4 (Q11): no reads; stage Ah1(t+2)->buf; vmcnt(6) (once/tile) ----
    stA(Tc2, 1, bufc);
    asm volatile("s_waitcnt vmcnt(6)" ::: "memory");
    __builtin_amdgcn_s_barrier();
    __builtin_amdgcn_s_setprio(1);
#pragma unroll
    for (int kk = 0; kk < 2; ++kk)
#pragma unroll
      for (int m3 = 0; m3 < 4; ++m3)
#pragma unroll
        for (int n2 = 0; n2 < 2; ++n2)
          acc[m3 + 4][n2 + 2] = __builtin_amdgcn_mfma_f32_16x16x32_bf16(a1[m3][kk], b1[n2][kk], acc[m3 + 4][n2 + 2], 0, 0, 0);
    __builtin_amdgcn_s_setprio(0);
    __builtin_amdgcn_s_barrier();
  };

  for (int t = 0; t < NT; t += 2) {
    tile_body(t,     IC<0>{}, IC<1>{});
    tile_body(t + 1, IC<1>{}, IC<0>{});
  }

  asm volatile("s_waitcnt vmcnt(0)" ::: "memory");

  // ---- epilogue: C/D layout col=lane&15, row=(lane>>4)*4+j ----
  int col = lane & 15;
  int rb = (lane >> 4) * 4;
#pragma unroll
  for (int n = 0; n < 4; ++n) {
    int gn = bn * BN + wc * 64 + n * 16 + col;
    float bsv = bias[gn];
#pragma unroll
    for (int m = 0; m < 8; ++m) {
      int gm = bm * BM + wr * 128 + m * 16 + rb;
#pragma unroll
      for (int j = 0; j < 4; ++j)
        C[(size_t)(gm + j) * N_TOT + gn] = acc[m][n][j] + bsv;
    }
  }
#undef GLLDS
}

__global__ void fill_kernel(float* p, int n, float v) {
  int stride = gridDim.x * blockDim.x;
  for (int i = blockIdx.x * blockDim.x + threadIdx.x; i < n; i += stride) p[i] = v;
}

extern "C" void kernel_launch(void* const* d_in, const int* in_sizes, int n_in,
                              void* d_out, int out_size, void* d_ws, size_t ws_size,
                              hipStream_t stream) {
  const float* x = (const float*)d_in[0];
  const int* wp = (const int*)d_in[1];
  const float* sc = (const float*)d_in[2];
  const float* bias = (const float*)d_in[3];
  float* out = (float*)d_out;

  size_t xb_bytes = (size_t)M_TOT * K_TOT * 2;  // 64 MiB
  size_t wb_bytes = (size_t)N_TOT * K_TOT * 2;  // 32 MiB
  if (ws_size < xb_bytes + wb_bytes) {
    fill_kernel<<<2048, 256, 0, stream>>>(out, out_size, 12345.0f);
    return;
  }
  u16* xb = (u16*)d_ws;
  u16* wb = (u16*)((char*)d_ws + xb_bytes);

  prep_kernel<<<2048, 256, 0, stream>>>(x, wp, sc, xb, wb);
  gemm_bf16_kernel<<<(M_TOT / BM) * (N_TOT / BN), 512, 0, stream>>>(xb, wb, bias, out);
}

// Round 13
// 261.905 us; speedup vs baseline: 1.0298x; 1.0298x over previous
//
#include <hip/hip_runtime.h>
#include <stdint.h>

#define M_TOT 8192
#define K_TOT 4096
#define N_TOT 4096
#define GROUPQ 32

#define BM 256
#define BN 256
#define BK 64
#define NT (K_TOT / BK)   // 64 K-tiles

typedef __bf16 bf16x8 __attribute__((ext_vector_type(8)));
typedef float f32x4 __attribute__((ext_vector_type(4)));
typedef unsigned short u16;
typedef unsigned short u16x8 __attribute__((ext_vector_type(8)));

template <int V> struct IC { static constexpr int value = V; };

__device__ __forceinline__ u16 f2bf_rne(float f) {
  union { float f; uint32_t u; } v; v.f = f;
  uint32_t u = v.u;
  uint32_t r = (u + 0x7FFFu + ((u >> 16) & 1u)) >> 16;  // round-nearest-even
  return (u16)r;
}

// ---- merged prepass: (a) x fp32 -> bf16, (b) dequant nibbles -> bf16 W ----
__global__ void prep_kernel(const float* __restrict__ x, const int* __restrict__ wp,
                            const float* __restrict__ sc,
                            u16* __restrict__ xb, u16* __restrict__ wb) {
  const int NCVT = M_TOT * K_TOT / 8;   // 8-elem chunks of x
  const int KH = K_TOT / 2;
  const int NDQ = N_TOT * KH / 8;       // 8-int chunks of w_packed
  int stride = gridDim.x * blockDim.x;
  int tid0 = blockIdx.x * blockDim.x + threadIdx.x;

  for (int i = tid0; i < NCVT; i += stride) {
    const float4* p = (const float4*)(x + (size_t)i * 8);
    float4 a = p[0];
    float4 b = p[1];
    u16x8 o;
    o[0] = f2bf_rne(a.x); o[1] = f2bf_rne(a.y); o[2] = f2bf_rne(a.z); o[3] = f2bf_rne(a.w);
    o[4] = f2bf_rne(b.x); o[5] = f2bf_rne(b.y); o[6] = f2bf_rne(b.z); o[7] = f2bf_rne(b.w);
    *(u16x8*)(xb + (size_t)i * 8) = o;
  }

  for (int t = tid0; t < NDQ; t += stride) {
    int base = t * 8;
    int o = base >> 11;                 // / (KH=2048)
    int ci = base & 2047;
    int e0 = ci * 2;
    float scale = sc[o * (K_TOT / GROUPQ) + (e0 >> 5)];
    int4 p0 = *(const int4*)(wp + base);
    int4 p1 = *(const int4*)(wp + base + 4);
    int v[8] = {p0.x, p0.y, p0.z, p0.w, p1.x, p1.y, p1.z, p1.w};
    u16x8 oA, oB;
#pragma unroll
    for (int j = 0; j < 8; ++j) {
      float lo = (float)((v[j] & 0xF) - 8) * scale;
      float hi = (float)(((v[j] >> 4) & 0xF) - 8) * scale;
      u16 lob = f2bf_rne(lo), hib = f2bf_rne(hi);
      if (j < 4) { oA[2 * j] = lob; oA[2 * j + 1] = hib; }
      else       { oB[2 * (j - 4)] = lob; oB[2 * (j - 4) + 1] = hib; }
    }
    u16* dst = wb + (size_t)o * K_TOT + e0;
    *(u16x8*)dst = oA;
    *(u16x8*)(dst + 8) = oB;
  }
}

// ---- main GEMM: round-11 structure (best verified: 234.6 us, MfmaUtil 52.5%)
// minus s_setprio (T5 is structure-conditional: null-to-negative on schedules
// without pre-MFMA-barrier role-split, per m190/m218b; r12 proved this
// schedule is not in T5's regime).
// 256x256, BK=64, 8 waves (2Mx4N), 16x16x32 MFMA; r7 schedule hand-unrolled x2
// with compile-time ping-pong index (all LDS addressing const-folded).
// Per tile: 4 phases, each = {ds_read NEXT phase's frags || stage || MFMA};
// barriers at end-p2, end-p3, boundary; boundary = lgkm0 + vmcnt(4) + barrier. ----
__global__ __launch_bounds__(512, 2) void gemm_bf16_kernel(
    const u16* __restrict__ A, const u16* __restrict__ Bt,
    const float* __restrict__ bias, float* __restrict__ C) {
  __shared__ alignas(16) u16 sL[65536];  // 128 KiB: A = [0,32768), B = [32768,65536)

  const int ntn = N_TOT / BN;            // 16
  int wg = blockIdx.x, nwg = gridDim.x;  // 512, %8==0
  int cpx = nwg >> 3;
  int swz = (wg & 7) * cpx + (wg >> 3);  // bijective XCD swizzle
  int bm = swz / ntn, bn = swz % ntn;

  int tid = threadIdx.x, wid = tid >> 6, lane = tid & 63;
  int wr = wid >> 2, wc = wid & 3;       // 2M x 4N waves
  const size_t K = K_TOT;

  // ---- staging addressing: half-tile = 128 rows x 64 cols, stored as two
  // k-planes of [128][32]; LDS chunk c holds global chunk c ^ ((row>>1)&3) ----
  int rowS = tid >> 2;                   // 0..127
  int cgS = (tid & 3) ^ ((rowS >> 1) & 3);
  const u16* pA = A + ((size_t)(bm * 256 + (rowS >> 6) * 128 + (rowS & 63))) * K + cgS * 8;
  const u16* pB = Bt + ((size_t)(bn * 256 + (rowS >> 5) * 64 + (rowS & 31))) * K + cgS * 8;
  u16* sE = &sL[0];

#define GLLDS(src, dst)                                                      \
  __builtin_amdgcn_global_load_lds(                                          \
      (const __attribute__((address_space(1))) uint32_t*)(src),              \
      (__attribute__((address_space(3))) uint32_t*)(dst), 16, 0, 0)

  auto stA = [&](int T, int mh, auto bufc) {  // A half mh of tile T -> buf (const)
    constexpr int buf = decltype(bufc)::value;
    const u16* s = pA + (size_t)mh * 64 * K + (size_t)T * 64;
    GLLDS(s,      sE + ((buf * 2 + 0) * 2 + mh) * 4096 + tid * 8);
    GLLDS(s + 32, sE + ((buf * 2 + 1) * 2 + mh) * 4096 + tid * 8);
  };
  auto stB = [&](int T, int nh, auto bufc) {
    constexpr int buf = decltype(bufc)::value;
    const u16* s = pB + (size_t)nh * 32 * K + (size_t)T * 64;
    GLLDS(s,      sE + 32768 + ((buf * 2 + 0) * 2 + nh) * 4096 + tid * 8);
    GLLDS(s + 32, sE + 32768 + ((buf * 2 + 1) * 2 + nh) * 4096 + tid * 8);
  };

  // ---- reader addressing (0-conflict per plane, same involution) ----
  int rA = wr * 64 + (lane & 15);
  int cA = ((lane >> 4) ^ ((rA >> 1) & 3)) * 8;
  int rB = wc * 32 + (lane & 15);
  int cB = ((lane >> 4) ^ ((rB >> 1) & 3)) * 8;
  const u16* rdA = sE + rA * 32 + cA;            // + const plane/frag offsets
  const u16* rdB = sE + 32768 + rB * 32 + cB;
  auto ldA = [&](auto bufc, int kk, int mh, int m3) {
    constexpr int buf = decltype(bufc)::value;
    return *(const bf16x8*)(rdA + ((buf * 2 + kk) * 2 + mh) * 4096 + m3 * 16 * 32);
  };
  auto ldB = [&](auto bufc, int kk, int nh, int n2) {
    constexpr int buf = decltype(bufc)::value;
    return *(const bf16x8*)(rdB + ((buf * 2 + kk) * 2 + nh) * 4096 + n2 * 16 * 32);
  };

  f32x4 acc[8][4] = {};
  bf16x8 a0[4][2], a1[4][2], b0[2][2], b1[2][2];

  // ---- prologue: stage tiles 0,1; vmcnt(4) leaves B1(1),A1(1) in flight ----
  stA(0, 0, IC<0>{}); stB(0, 0, IC<0>{}); stB(0, 1, IC<0>{}); stA(0, 1, IC<0>{});
  stA(1, 0, IC<1>{}); stB(1, 0, IC<1>{}); stB(1, 1, IC<1>{}); stA(1, 1, IC<1>{});
  asm volatile("s_waitcnt vmcnt(4)" ::: "memory");
  __builtin_amdgcn_s_barrier();

  // prime: A0(0), B0(0)
#pragma unroll
  for (int m3 = 0; m3 < 4; ++m3)
#pragma unroll
    for (int kk = 0; kk < 2; ++kk) a0[m3][kk] = ldA(IC<0>{}, kk, 0, m3);
#pragma unroll
  for (int n2 = 0; n2 < 2; ++n2)
#pragma unroll
    for (int kk = 0; kk < 2; ++kk) b0[n2][kk] = ldB(IC<0>{}, kk, 0, n2);
  asm volatile("s_waitcnt lgkmcnt(0)" ::: "memory");
  __builtin_amdgcn_s_barrier();

  auto tile_body = [&](int t, auto bufc, auto nbufc) {
    bool st_ok = (t + 2 < NT);
    bool rd_ok = (t + 1 < NT);
    int Ts = t + 2;

    // ---- p1: read B1(t); stage A0(t+2); MFMA (A0,B0); NO barrier ----
#pragma unroll
    for (int n2 = 0; n2 < 2; ++n2)
#pragma unroll
      for (int kk = 0; kk < 2; ++kk) b1[n2][kk] = ldB(bufc, kk, 1, n2);
    if (st_ok) stA(Ts, 0, bufc);
#pragma unroll
    for (int kk = 0; kk < 2; ++kk)
#pragma unroll
      for (int m3 = 0; m3 < 4; ++m3)
#pragma unroll
        for (int n2 = 0; n2 < 2; ++n2)
          acc[m3][n2] = __builtin_amdgcn_mfma_f32_16x16x32_bf16(a0[m3][kk], b0[n2][kk], acc[m3][n2], 0, 0, 0);

    // ---- p2: read A1(t); stage B0(t+2); MFMA (A0,B1); barrier (frees B1) ----
#pragma unroll
    for (int m3 = 0; m3 < 4; ++m3)
#pragma unroll
      for (int kk = 0; kk < 2; ++kk) a1[m3][kk] = ldA(bufc, kk, 1, m3);
    if (st_ok) stB(Ts, 0, bufc);
#pragma unroll
    for (int kk = 0; kk < 2; ++kk)
#pragma unroll
      for (int m3 = 0; m3 < 4; ++m3)
#pragma unroll
        for (int n2 = 0; n2 < 2; ++n2)
          acc[m3][n2 + 2] = __builtin_amdgcn_mfma_f32_16x16x32_bf16(a0[m3][kk], b1[n2][kk], acc[m3][n2 + 2], 0, 0, 0);
    __builtin_amdgcn_s_barrier();

    // ---- p3: read A0(t+1); stage B1(t+2); MFMA (A1,B0); barrier (frees A1) ----
    if (rd_ok) {
#pragma unroll
      for (int m3 = 0; m3 < 4; ++m3)
#pragma unroll
        for (int kk = 0; kk < 2; ++kk) a0[m3][kk] = ldA(nbufc, kk, 0, m3);
    }
    if (st_ok) stB(Ts, 1, bufc);
#pragma unroll
    for (int kk = 0; kk < 2; ++kk)
#pragma unroll
      for (int m3 = 0; m3 < 4; ++m3)
#pragma unroll
        for (int n2 = 0; n2 < 2; ++n2)
          acc[m3 + 4][n2] = __builtin_amdgcn_mfma_f32_16x16x32_bf16(a1[m3][kk], b0[n2][kk], acc[m3 + 4][n2], 0, 0, 0);
    __builtin_amdgcn_s_barrier();

    // ---- p4: read B0(t+1); stage A1(t+2); MFMA (A1,B1); boundary ----
    if (rd_ok) {
#pragma unroll
      for (int n2 = 0; n2 < 2; ++n2)
#pragma unroll
        for (int kk = 0; kk < 2; ++kk) b0[n2][kk] = ldB(nbufc, kk, 0, n2);
    }
    if (st_ok) stA(Ts, 1, bufc);
#pragma unroll
    for (int kk = 0; kk < 2; ++kk)
#pragma unroll
      for (int m3 = 0; m3 < 4; ++m3)
#pragma unroll
        for (int n2 = 0; n2 < 2; ++n2)
          acc[m3 + 4][n2 + 2] = __builtin_amdgcn_mfma_f32_16x16x32_bf16(a1[m3][kk], b1[n2][kk], acc[m3 + 4][n2 + 2], 0, 0, 0);
    asm volatile("s_waitcnt lgkmcnt(0)" ::: "memory");
    if (t < NT - 2) { asm volatile("s_waitcnt vmcnt(4)" ::: "memory"); }
    else            { asm volatile("s_waitcnt vmcnt(0)" ::: "memory"); }
    __builtin_amdgcn_s_barrier();
  };

  for (int t = 0; t < NT; t += 2) {
    tile_body(t,     IC<0>{}, IC<1>{});
    tile_body(t + 1, IC<1>{}, IC<0>{});
  }

  asm volatile("s_waitcnt vmcnt(0)" ::: "memory");

  // ---- epilogue: C/D layout col=lane&15, row=(lane>>4)*4+j ----
  int col = lane & 15;
  int rb = (lane >> 4) * 4;
#pragma unroll
  for (int n = 0; n < 4; ++n) {
    int gn = bn * BN + wc * 64 + n * 16 + col;
    float bsv = bias[gn];
#pragma unroll
    for (int m = 0; m < 8; ++m) {
      int gm = bm * BM + wr * 128 + m * 16 + rb;
#pragma unroll
      for (int j = 0; j < 4; ++j)
        C[(size_t)(gm + j) * N_TOT + gn] = acc[m][n][j] + bsv;
    }
  }
#undef GLLDS
}

__global__ void fill_kernel(float* p, int n, float v) {
  int stride = gridDim.x * blockDim.x;
  for (int i = blockIdx.x * blockDim.x + threadIdx.x; i < n; i += stride) p[i] = v;
}

extern "C" void kernel_launch(void* const* d_in, const int* in_sizes, int n_in,
                              void* d_out, int out_size, void* d_ws, size_t ws_size,
                              hipStream_t stream) {
  const float* x = (const float*)d_in[0];
  const int* wp = (const int*)d_in[1];
  const float* sc = (const float*)d_in[2];
  const float* bias = (const float*)d_in[3];
  float* out = (float*)d_out;

  size_t xb_bytes = (size_t)M_TOT * K_TOT * 2;  // 64 MiB
  size_t wb_bytes = (size_t)N_TOT * K_TOT * 2;  // 32 MiB
  if (ws_size < xb_bytes + wb_bytes) {
    fill_kernel<<<2048, 256, 0, stream>>>(out, out_size, 12345.0f);
    return;
  }
  u16* xb = (u16*)d_ws;
  u16* wb = (u16*)((char*)d_ws + xb_bytes);

  prep_kernel<<<2048, 256, 0, stream>>>(x, wp, sc, xb, wb);
  gemm_bf16_kernel<<<(M_TOT / BM) * (N_TOT / BN), 512, 0, stream>>>(xb, wb, bias, out);
}